// Round 2
// baseline (13970.786 us; speedup 1.0000x reference)
//
#include <hip/hip_runtime.h>
#include <hip/hip_bf16.h>

// Shapes (fixed by the problem)
#define BATCH 256
#define ENCH  512   // encoder hidden (e)
#define WWID  256   // encoder width  (w)
#define ATT   256   // attn size      (a)
#define DECH  256   // decoder hidden (d)
#define EMBD  128
#define VOC   81
#define TT    100

// ---------- numerics: fp32, libm-grade (trajectory must match np fp32 ref) ----
__device__ __forceinline__ float ftanh(float x) {
  // tanh(x) = 1 - 2/(exp(2x)+1); expf is ~1ulp OCML, plain div is IEEE.
  float e = expf(2.0f * x);
  return 1.0f - 2.0f / (e + 1.0f);
}
__device__ __forceinline__ float fsig(float x) {
  return 1.0f / (1.0f + expf(-x));
}

// ---------------- init: zero h (in xkT0 rows 512..767), c, x=sos -------------
__global__ void k_init(float* __restrict__ cbuf, float* __restrict__ xkT0_h,
                       int* __restrict__ xbuf, const int* __restrict__ sos) {
  int idx = blockIdx.x * 256 + threadIdx.x;
  if (blockIdx.x < 256) {
    cbuf[idx] = 0.0f;
    xkT0_h[idx] = 0.0f;
  } else {
    xbuf[threadIdx.x] = sos[0];
  }
}

// ------------- build transposed weights: W2[k][j], DW2[k][a] -----------------
// W2 rows 0..511 = w_ih[:,128+k]^T (context part), rows 512..767 = w_hh^T
__global__ void k_build(const float* __restrict__ w_ih, const float* __restrict__ w_hh,
                        const float* __restrict__ dlw,
                        float* __restrict__ W2, float* __restrict__ DW2) {
  int k = blockIdx.x, tid = threadIdx.x;
  if (k < 768) {
    for (int j = tid; j < 1024; j += 256)
      W2[(size_t)k * 1024 + j] = (k < 512) ? w_ih[(size_t)j * 640 + 128 + k]
                                           : w_hh[(size_t)j * 256 + (k - 512)];
  } else {
    int kk = k - 768;
    DW2[kk * 256 + tid] = dlw[tid * 256 + kk];
  }
}

// ---------- emb_gates[v][j] = b_ih[j]+b_hh[j] + sum_e emb[v][e] w_ih[j][e] ----
__global__ void k_embg(const float* __restrict__ emb, const float* __restrict__ w_ih,
                       const float* __restrict__ b_ih, const float* __restrict__ b_hh,
                       float* __restrict__ embg) {
  int v = blockIdx.x, tid = threadIdx.x;
  __shared__ float em[EMBD];
  if (tid < EMBD) em[tid] = emb[v * EMBD + tid];
  __syncthreads();
  for (int j = tid; j < 1024; j += 256) {
    float s = b_ih[j] + b_hh[j];
    const float* wr = w_ih + (size_t)j * 640;
#pragma unroll 8
    for (int e = 0; e < EMBD; ++e) s += em[e] * wr[e];
    embg[v * 1024 + j] = s;
  }
}

// ------------- weighted_enc[b][a][w] = sum_e cw[a][e] enc[b][e][w] + cb[a] ----
// grid 4096 = b(256) * a-tile(4 of 64) * w-tile(4 of 64); 256 threads, 4x4/thread
__global__ void __launch_bounds__(256) k_we(const float* __restrict__ enc,
                                            const float* __restrict__ cw,
                                            const float* __restrict__ cb,
                                            float* __restrict__ we) {
  int bid = blockIdx.x;
  int b = bid >> 4, at = (bid >> 2) & 3, wt = bid & 3;
  int a0 = at * 64, w0 = wt * 64;
  __shared__ float cwT[32][68];   // [e][a] (transposed), pad for banks/align
  __shared__ float encT[32][64];  // [e][w]
  int tid = threadIdx.x;
  int tx = tid & 15, ty = tid >> 4;
  float acc[4][4] = {};
  const float* encB = enc + (size_t)b * ENCH * WWID;
  for (int k0 = 0; k0 < ENCH; k0 += 32) {
    {
      int a = tid >> 2, e8 = (tid & 3) * 8;
      const float* src = cw + (size_t)(a0 + a) * ENCH + k0 + e8;
      float4 v0 = *(const float4*)(src);
      float4 v1 = *(const float4*)(src + 4);
      cwT[e8 + 0][a] = v0.x; cwT[e8 + 1][a] = v0.y; cwT[e8 + 2][a] = v0.z; cwT[e8 + 3][a] = v0.w;
      cwT[e8 + 4][a] = v1.x; cwT[e8 + 5][a] = v1.y; cwT[e8 + 6][a] = v1.z; cwT[e8 + 7][a] = v1.w;
    }
    {
      int e = tid >> 3, w8 = (tid & 7) * 8;
      const float* src = encB + (size_t)(k0 + e) * WWID + w0 + w8;
      *(float4*)&encT[e][w8] = *(const float4*)src;
      *(float4*)&encT[e][w8 + 4] = *(const float4*)(src + 4);
    }
    __syncthreads();
#pragma unroll
    for (int e = 0; e < 32; ++e) {
      float4 av = *(const float4*)&cwT[e][ty * 4];
      float4 bv = *(const float4*)&encT[e][tx * 4];
      float a4[4] = {av.x, av.y, av.z, av.w};
      float b4[4] = {bv.x, bv.y, bv.z, bv.w};
#pragma unroll
      for (int i = 0; i < 4; ++i)
#pragma unroll
        for (int j = 0; j < 4; ++j) acc[i][j] += a4[i] * b4[j];
    }
    __syncthreads();
  }
#pragma unroll
  for (int i = 0; i < 4; ++i) {
    int a = a0 + ty * 4 + i;
    float bias = cb[a];
    float4 o;
    o.x = acc[i][0] + bias; o.y = acc[i][1] + bias;
    o.z = acc[i][2] + bias; o.w = acc[i][3] + bias;
    *(float4*)(we + ((size_t)(b * ATT + a)) * WWID + w0 + tx * 4) = o;
  }
}

// ---------------- K1: dp[b][a] = sum_k h[b][k] dlw[a][k] + db[a] -------------
// h read from xkT rows 512.. (wave-uniform address -> scalar loads)
__global__ void __launch_bounds__(256) k_dp(const float* __restrict__ xkT,
                                            const float* __restrict__ DW2,
                                            const float* __restrict__ db,
                                            float* __restrict__ dp) {
  int b0 = blockIdx.x * 4;
  int a = threadIdx.x;
  float a0 = 0, a1 = 0, a2 = 0, a3 = 0;
  for (int k = 0; k < DECH; ++k) {
    float dv = DW2[k * 256 + a];
    const float* hr = xkT + (size_t)(512 + k) * 256 + b0;
    a0 += dv * hr[0]; a1 += dv * hr[1]; a2 += dv * hr[2]; a3 += dv * hr[3];
  }
  float bb = db[a];
  dp[(b0 + 0) * 256 + a] = a0 + bb;
  dp[(b0 + 1) * 256 + a] = a1 + bb;
  dp[(b0 + 2) * 256 + a] = a2 + bb;
  dp[(b0 + 3) * 256 + a] = a3 + bb;
}

// --------- K2: scores -> softmax -> attns out; context -> ctxT[e][b] ---------
__global__ void __launch_bounds__(512) k_attn(const float* __restrict__ we,
                                              const float* __restrict__ enc,
                                              const float* __restrict__ dp,
                                              const float* __restrict__ ew,
                                              const float* __restrict__ eb,
                                              float* __restrict__ ctxT,
                                              float* __restrict__ out, int t) {
  int b = blockIdx.x, tid = threadIdx.x;
  __shared__ float dp_s[256], ew_s[256], sc_s[256];
  __shared__ float part[8][64][4];
  __shared__ float red[8];
  if (tid < 256) { dp_s[tid] = dp[b * 256 + tid]; ew_s[tid] = ew[tid]; }
  __syncthreads();
  int q = tid & 63, pt = tid >> 6;
  const float* weB = we + ((size_t)b << 16);
  float s0 = 0, s1 = 0, s2 = 0, s3 = 0;
  int abase = pt * 32;
#pragma unroll 4
  for (int i = 0; i < 32; ++i) {
    int aa = abase + i;
    float4 wv = *(const float4*)(weB + (size_t)aa * 256 + q * 4);
    float d = dp_s[aa], w8 = ew_s[aa];
    s0 += w8 * ftanh(wv.x + d);
    s1 += w8 * ftanh(wv.y + d);
    s2 += w8 * ftanh(wv.z + d);
    s3 += w8 * ftanh(wv.w + d);
  }
  part[pt][q][0] = s0; part[pt][q][1] = s1; part[pt][q][2] = s2; part[pt][q][3] = s3;
  __syncthreads();
  float sv = 0.0f;
  if (tid < 256) {
    sv = eb[0];
#pragma unroll
    for (int p = 0; p < 8; ++p) sv += part[p][tid >> 2][tid & 3];
    float mm = sv;
    for (int off = 32; off; off >>= 1) mm = fmaxf(mm, __shfl_xor(mm, off));
    if ((tid & 63) == 0) red[tid >> 6] = mm;
  }
  __syncthreads();
  float m = fmaxf(fmaxf(red[0], red[1]), fmaxf(red[2], red[3]));
  float p = 0.0f;
  if (tid < 256) {
    p = expf(sv - m);
    float ss = p;
    for (int off = 32; off; off >>= 1) ss += __shfl_xor(ss, off);
    if ((tid & 63) == 0) red[4 + (tid >> 6)] = ss;
  }
  __syncthreads();
  float S = red[4] + red[5] + red[6] + red[7];
  if (tid < 256) {
    float alpha = p / S;
    sc_s[tid] = alpha;
    out[(size_t)(BATCH * TT * VOC) + (size_t)(BATCH * TT) + ((size_t)b * TT + t) * WWID + tid] =
        alpha;
  }
  __syncthreads();
  // context[b][e] = sum_w enc[b][e][w] * alpha[w]; write transposed ctxT[e][b]
  int lane = tid & 63, wvi = tid >> 6;
  const float* encB = enc + (size_t)b * ENCH * WWID;
  float4 al = *(const float4*)&sc_s[lane * 4];
#pragma unroll 2
  for (int e = wvi; e < ENCH; e += 8) {
    float4 evv = *(const float4*)(encB + (size_t)e * WWID + lane * 4);
    float s = evv.x * al.x + evv.y * al.y + evv.z * al.z + evv.w * al.w;
    for (int off = 32; off; off >>= 1) s += __shfl_xor(s, off);
    if (lane == 0) ctxT[(size_t)e * BATCH + b] = s;
  }
}

// --------- K3: gates GEMM (K=768, K-split 4) + LSTM cell fused ---------------
// grid 256 = b-tile(16 of 16) x j-tile(16 of 16); xk via wave-uniform loads
__global__ void __launch_bounds__(256) k_gates(const float* __restrict__ W2,
                                               const float* __restrict__ xkT,
                                               float* __restrict__ xkT_nxt,
                                               const float* __restrict__ embg,
                                               const int* __restrict__ xbuf,
                                               float* __restrict__ cbuf,
                                               float* __restrict__ hplain) {
  int bt = blockIdx.x >> 4, jt = blockIdx.x & 15;
  int b0 = bt * 16;
  int tid = threadIdx.x;
  int ks = tid >> 6, r = tid & 63;
  int gate = r >> 4, jl = r & 15;
  int grow = gate * 256 + jt * 16 + jl;
  __shared__ float part[4][64][17];
  __shared__ int x_s[16];
  if (tid < 16) x_s[tid] = xbuf[b0 + tid];
  float acc[16] = {};
  int k0 = ks * 192;
  for (int k = k0; k < k0 + 192; ++k) {
    float wv = W2[(size_t)k * 1024 + grow];
    const float* xr = xkT + (size_t)k * 256 + b0;
#pragma unroll
    for (int bi = 0; bi < 16; ++bi) acc[bi] += wv * xr[bi];
  }
#pragma unroll
  for (int bi = 0; bi < 16; ++bi) part[ks][r][bi] = acc[bi];
  __syncthreads();
  int b = tid >> 4, jj = tid & 15;
  float g4[4];
#pragma unroll
  for (int g = 0; g < 4; ++g) {
    int rr = g * 16 + jj;
    g4[g] = part[0][rr][b] + part[1][rr][b] + part[2][rr][b] + part[3][rr][b];
  }
  const float* er = embg + (size_t)x_s[b] * 1024 + jt * 16 + jj;
  float iv = fsig(g4[0] + er[0]);
  float fv = fsig(g4[1] + er[256]);
  float gv = ftanh(g4[2] + er[512]);
  float ov = fsig(g4[3] + er[768]);
  int cidx = (b0 + b) * 256 + jt * 16 + jj;
  float cn = fv * cbuf[cidx] + iv * gv;
  float hn = ov * ftanh(cn);
  cbuf[cidx] = cn;
  hplain[cidx] = hn;
  xkT_nxt[(size_t)(512 + jt * 16 + jj) * 256 + b0 + b] = hn;
}

// --------- K4: logits GEMV + log_softmax + argmax (greedy feedback) ----------
__global__ void __launch_bounds__(256) k_logits(const float* __restrict__ hplain,
                                                const float* __restrict__ ow,
                                                const float* __restrict__ ob,
                                                float* __restrict__ out,
                                                int* __restrict__ xbuf, int t) {
  int b = blockIdx.x, tid = threadIdx.x;
  __shared__ float h_s[256];
  __shared__ float lg[VOC];
  __shared__ float logp_s[VOC];
  __shared__ float red[8];
  h_s[tid] = hplain[b * 256 + tid];
  __syncthreads();
  int lane = tid & 63, wv = tid >> 6;
  float4 hh = *(const float4*)&h_s[lane * 4];
  for (int v = wv; v < VOC; v += 4) {
    float4 wr = *(const float4*)(ow + (size_t)v * 256 + lane * 4);
    float s = wr.x * hh.x + wr.y * hh.y + wr.z * hh.z + wr.w * hh.w;
    for (int off = 32; off; off >>= 1) s += __shfl_xor(s, off);
    if (lane == 0) lg[v] = s + ob[v];
  }
  __syncthreads();
  float v_ = (tid < VOC) ? lg[tid] : -3.402823e38f;
  float mm = v_;
  for (int off = 32; off; off >>= 1) mm = fmaxf(mm, __shfl_xor(mm, off));
  if ((tid & 63) == 0) red[tid >> 6] = mm;
  __syncthreads();
  float m = fmaxf(fmaxf(red[0], red[1]), fmaxf(red[2], red[3]));
  float p = (tid < VOC) ? expf(v_ - m) : 0.0f;
  float ss = p;
  for (int off = 32; off; off >>= 1) ss += __shfl_xor(ss, off);
  if ((tid & 63) == 0) red[4 + (tid >> 6)] = ss;
  __syncthreads();
  float S = red[4] + red[5] + red[6] + red[7];
  float lse = m + logf(S);
  if (tid < VOC) {
    float lp = v_ - lse;
    logp_s[tid] = lp;
    out[((size_t)b * TT + t) * VOC + tid] = lp;
  }
  __syncthreads();
  if (tid == 0) {
    int best = 0;
    float bv = logp_s[0];
    for (int v = 1; v < VOC; ++v) {
      float x = logp_s[v];
      if (x > bv) { bv = x; best = v; }
    }
    xbuf[b] = best;
    out[(size_t)(BATCH * TT * VOC) + (size_t)b * TT + t] = (float)best;
  }
}

extern "C" void kernel_launch(void* const* d_in, const int* in_sizes, int n_in,
                              void* d_out, int out_size, void* d_ws, size_t ws_size,
                              hipStream_t stream) {
  (void)in_sizes; (void)n_in; (void)out_size; (void)ws_size;
  const float* enc = (const float*)d_in[0];
  const float* emb = (const float*)d_in[1];
  const float* ecw = (const float*)d_in[2];
  const float* ecb = (const float*)d_in[3];
  const float* dlw = (const float*)d_in[4];
  const float* dlb = (const float*)d_in[5];
  const float* ew  = (const float*)d_in[6];
  const float* eb  = (const float*)d_in[7];
  const float* wih = (const float*)d_in[8];
  const float* whh = (const float*)d_in[9];
  const float* bih = (const float*)d_in[10];
  const float* bhh = (const float*)d_in[11];
  const float* ow  = (const float*)d_in[12];
  const float* ob  = (const float*)d_in[13];
  const int* sos   = (const int*)d_in[15];
  float* out = (float*)d_out;
  float* ws = (float*)d_ws;

  // workspace map (floats); total ~18.2M floats ~ 73 MB
  size_t off = 0;
  float* we    = ws + off; off += (size_t)BATCH * ATT * WWID;  // 16,777,216
  float* W2    = ws + off; off += (size_t)768 * 1024;
  float* DW2   = ws + off; off += (size_t)256 * 256;
  float* embg  = ws + off; off += (size_t)VOC * 1024;
  off = (off + 255) & ~(size_t)255;
  float* xkT0  = ws + off; off += (size_t)768 * 256;  // rows 0..511 ctx, 512..767 h
  float* xkT1  = ws + off; off += (size_t)768 * 256;
  float* cbuf  = ws + off; off += (size_t)256 * 256;
  float* hplain= ws + off; off += (size_t)256 * 256;
  float* dp    = ws + off; off += (size_t)256 * 256;
  int* xbuf    = (int*)(ws + off); off += 256;

  k_init<<<257, 256, 0, stream>>>(cbuf, xkT0 + (size_t)512 * 256, xbuf, sos);
  k_build<<<1024, 256, 0, stream>>>(wih, whh, dlw, W2, DW2);
  k_embg<<<VOC, 256, 0, stream>>>(emb, wih, bih, bhh, embg);
  k_we<<<4096, 256, 0, stream>>>(enc, ecw, ecb, we);

  for (int t = 0; t < TT; ++t) {
    float* xc = (t & 1) ? xkT1 : xkT0;
    float* xn = (t & 1) ? xkT0 : xkT1;
    k_dp<<<64, 256, 0, stream>>>(xc, DW2, dlb, dp);
    k_attn<<<256, 512, 0, stream>>>(we, enc, dp, ew, eb, xc, out, t);
    k_gates<<<256, 256, 0, stream>>>(W2, xc, xn, embg, xbuf, cbuf, hplain);
    k_logits<<<256, 256, 0, stream>>>(hplain, ow, ob, out, xbuf, t);
  }
}